// Round 9
// baseline (151.651 us; speedup 1.0000x reference)
//
#include <hip/hip_runtime.h>
#include <cstdint>

#define NNODES 50000
#define NEDGES 800000
#define NEG 0.2f
#define NBKT 196        // buckets of 256 nodes: 196*256 = 50176 >= 50000
#define BCAP 5120       // per-bucket capacity (mean 4096, sd 64 -> 16 sigma headroom)
#define GEMM_BLOCKS 782 // ceil(50000/64)

typedef __attribute__((ext_vector_type(8))) short short8;   // 8 bf16 (4 VGPRs)
typedef __attribute__((ext_vector_type(4))) float f32x4;

#define AS_STRIDE 136   // ushorts; 272B rows -> 16B aligned
#define CS_STRIDE 132   // floats; breaks 128-mod-32 bank aliasing

__device__ __forceinline__ float leaky(float v) { return v > 0.f ? v : NEG * v; }

__device__ __forceinline__ unsigned short f2bf(float f) {   // round-to-nearest-even
    unsigned int u = __float_as_uint(f);
    u += 0x7fff + ((u >> 16) & 1);
    return (unsigned short)(u >> 16);
}

// block exclusive scan (shfl within wave + LDS across NW waves)
template <int NW>
__device__ __forceinline__ int block_excl_scan(int v, int t) {
    __shared__ int wsum[NW];
    const int lane = t & 63, wv = t >> 6;
    int x = v;
    #pragma unroll
    for (int m = 1; m < 64; m <<= 1) {
        int u = __shfl_up(x, m);
        if (lane >= m) x += u;
    }
    if (lane == 63) wsum[wv] = x;
    __syncthreads();
    if (t == 0) {
        int run = 0;
        #pragma unroll
        for (int i = 0; i < NW; ++i) { int tmp = wsum[i]; wsum[i] = run; run += tmp; }
    }
    __syncthreads();
    return x - v + wsum[wv];
}

// K1 prep: blocks [0,196) = edge binning by dst>>8 (the long pole, launched
// first); blocks [196,212) = W (fp32) -> Wt (bf16, n-major); block 212 =
// battf logit-fragment table. bin and wt have independent inputs ->
// co-scheduled instead of serialized (saves the wt_k serial prefix).
__global__ __launch_bounds__(256) void prep_k(const float* __restrict__ W,
                                              const float* __restrict__ att_src,
                                              const float* __restrict__ att_dst,
                                              unsigned short* __restrict__ wt,
                                              uint4* __restrict__ battf,
                                              const int* __restrict__ ei,
                                              int* __restrict__ bcnt,
                                              unsigned int* __restrict__ bktdata) {
    __shared__ __align__(16) char smem[19712];
    const int t = threadIdx.x;

    if (blockIdx.x < NBKT) {
        // ---------------- BIN part ----------------
        int* lhist = (int*)smem;                    // [NBKT]
        int* lofs  = lhist + NBKT;
        int* lcur  = lofs + NBKT;
        int* gbase = lcur + NBKT;
        unsigned int* staged = (unsigned int*)(gbase + NBKT);  // [4096]
        const int b = blockIdx.x;
        for (int i = t; i < NBKT; i += 256) lhist[i] = 0;
        __syncthreads();
        unsigned int pk[16];
        int bk[16];
        const int e0 = b * 4096;
        #pragma unroll
        for (int i = 0; i < 16; ++i) {
            int e = e0 + i * 256 + t;
            if (e < NEDGES) {
                int s = ei[e], d = ei[NEDGES + e];
                bk[i] = d >> 8;
                pk[i] = ((unsigned)bk[i] << 24) | ((unsigned)(d & 255) << 16) | (unsigned)s;
                atomicAdd(&lhist[bk[i]], 1);
            } else bk[i] = -1;
        }
        __syncthreads();
        int v = (t < NBKT) ? lhist[t] : 0;
        int excl = block_excl_scan<4>(v, t);
        if (t < NBKT) { lofs[t] = excl; lcur[t] = excl; }
        __syncthreads();
        if (t < NBKT) gbase[t] = (v > 0) ? atomicAdd(&bcnt[t], v) : 0;
        #pragma unroll
        for (int i = 0; i < 16; ++i) {
            if (bk[i] >= 0) {
                int pos = atomicAdd(&lcur[bk[i]], 1);
                staged[pos] = pk[i];
            }
        }
        __syncthreads();
        const int total = lofs[NBKT - 1] + lhist[NBKT - 1];
        for (int i = t; i < total; i += 256) {
            unsigned int ent = staged[i];
            int bb = ent >> 24;
            int pos = gbase[bb] + (i - lofs[bb]);
            bktdata[(size_t)bb * BCAP + pos] = ent & 0x00FFFFFFu;
        }
    } else if (blockIdx.x < NBKT + 16) {
        // ---------------- Wt conversion ----------------
        int i = (blockIdx.x - NBKT) * 256 + t;   // [0, 4096)
        int k = i >> 5, n4 = (i & 31) * 4;
        float4 wv = ((const float4*)W)[i];
        wt[(n4 + 0) * 128 + k] = f2bf(wv.x);
        wt[(n4 + 1) * 128 + k] = f2bf(wv.y);
        wt[(n4 + 2) * 128 + k] = f2bf(wv.z);
        wt[(n4 + 3) * 128 + k] = f2bf(wv.w);
    } else {
        // ---------------- battf table ----------------
        float* wsd = (float*)smem;   // [2][128][4]
        const int k = t & 127, which = t >> 7;
        const float* av = which ? att_dst : att_src;
        #pragma unroll
        for (int h = 0; h < 4; ++h) {
            float s = 0.f;
            #pragma unroll
            for (int c4 = 0; c4 < 8; ++c4) {
                float4 wv = ((const float4*)(W + k * 128 + h * 32))[c4];
                float4 a  = ((const float4*)(av + h * 32))[c4];
                s += wv.x * a.x + wv.y * a.y + wv.z * a.z + wv.w * a.w;
            }
            wsd[(which * 128 + k) * 4 + h] = s;
        }
        __syncthreads();
        // battf[s*64+lane] = 8 bf16 of B_att[n=m16][k=s*32+quad*8+j]
        const int s = t >> 6, lane = t & 63;
        const int quad = lane >> 4, m16 = lane & 15;
        unsigned short fr[8];
        #pragma unroll
        for (int j = 0; j < 8; ++j) {
            int kk = s * 32 + quad * 8 + j;
            float v = 0.f;
            if (m16 < 4)      v = wsd[(0 * 128 + kk) * 4 + m16];
            else if (m16 < 8) v = wsd[(1 * 128 + kk) * 4 + (m16 - 4)];
            fr[j] = f2bf(v);
        }
        battf[s * 64 + lane] = make_uint4(
            ((unsigned)fr[1] << 16) | fr[0], ((unsigned)fr[3] << 16) | fr[2],
            ((unsigned)fr[5] << 16) | fr[4], ((unsigned)fr[7] << 16) | fr[6]);
    }
}

// K2 main: blocks [0,196) = per-bucket counting sort (needs only bin output,
// launched FIRST so it overlaps the GEMM bulk); blocks [196,978) = bf16-MFMA
// gemm (h=x@W, bf16 store; logits via a 9th MFMA tile from battf).
// sort is hidden under the GEMM instead of being a serial stage.
__global__ __launch_bounds__(256) void main_k(const float* __restrict__ x,
                                              const unsigned short* __restrict__ wt,
                                              const uint4* __restrict__ battf,
                                              unsigned short* __restrict__ hb,
                                              float* __restrict__ a_src,
                                              float* __restrict__ a_dst,
                                              const int* __restrict__ bcnt,
                                              const unsigned int* __restrict__ bktdata,
                                              int* __restrict__ off,
                                              int* __restrict__ csr) {
    __shared__ __align__(16) char smem[52224];
    const int tid = threadIdx.x;

    if (blockIdx.x < NBKT) {
        // ---------------- SORT part ----------------
        unsigned int* staged = (unsigned int*)smem;        // [BCAP] 20480B
        int* lcnt = (int*)(smem + 20480);                  // [256]
        int* lcur = (int*)(smem + 21504);                  // [256]
        __shared__ int sbase, scnt;
        const int b = blockIdx.x, t = tid;
        int bv = (t < NBKT) ? bcnt[t] : 0;
        int bexcl = block_excl_scan<4>(bv, t);
        if (t == b) { sbase = bexcl; scnt = bv; }
        lcnt[t] = 0;
        __syncthreads();
        const int cnt = scnt, base = sbase;
        for (int i = t; i < cnt; i += 256) staged[i] = bktdata[(size_t)b * BCAP + i];
        __syncthreads();
        for (int i = t; i < cnt; i += 256) atomicAdd(&lcnt[(staged[i] >> 16) & 0xFF], 1);
        __syncthreads();
        int v = lcnt[t];
        int excl = block_excl_scan<4>(v, t);
        lcur[t] = excl;
        const int node = b * 256 + t;
        if (node <= NNODES) off[node] = base + excl;
        __syncthreads();
        for (int i = t; i < cnt; i += 256) {
            unsigned int ent = staged[i];
            int pos = atomicAdd(&lcur[(ent >> 16) & 0xFF], 1);
            csr[base + pos] = (int)(ent & 0xFFFFu);
        }
    } else {
        // ---------------- GEMM part ----------------
        unsigned short* As = (unsigned short*)smem;            // [64][AS_STRIDE] bf16
        unsigned short* Bs = (unsigned short*)(smem + 17408);  // WT [128][AS_STRIDE] bf16
        float*          Cs = (float*)smem;                     // [64][CS_STRIDE] fp32 (aliases)
        const int rbase = (blockIdx.x - NBKT) * 64;

        // stage A: x rows fp32 -> bf16 LDS
        #pragma unroll
        for (int i = 0; i < 8; ++i) {
            int f = tid + i * 256;           // float4 index; 32 per row
            int r = f >> 5, c4 = (f & 31) * 4;
            float4 xv = make_float4(0.f, 0.f, 0.f, 0.f);
            if (rbase + r < NNODES) xv = ((const float4*)x)[(size_t)(rbase + r) * 32 + (f & 31)];
            unsigned int p0 = ((unsigned int)f2bf(xv.y) << 16) | f2bf(xv.x);
            unsigned int p1 = ((unsigned int)f2bf(xv.w) << 16) | f2bf(xv.z);
            *(uint2*)(As + r * AS_STRIDE + c4) = make_uint2(p0, p1);
        }
        // stage B: Wt (bf16, n-major) -> LDS, 16B chunks, coalesced
        #pragma unroll
        for (int i = 0; i < 8; ++i) {
            int c = tid + i * 256;           // 16B chunk id, [0, 2048)
            int n = c >> 4, k8 = (c & 15) * 8;
            uint4 wv = ((const uint4*)wt)[c];
            *(uint4*)(Bs + n * AS_STRIDE + k8) = wv;
        }
        __syncthreads();

        const int lane = tid & 63, w = tid >> 6;
        const int quad = lane >> 4, m16 = lane & 15;

        short8 af[4];
        #pragma unroll
        for (int s = 0; s < 4; ++s)
            af[s] = *(const short8*)(As + (w * 16 + m16) * AS_STRIDE + s * 32 + quad * 8);

        f32x4 acc[8];
        #pragma unroll
        for (int t = 0; t < 8; ++t) acc[t] = (f32x4){0.f, 0.f, 0.f, 0.f};

        #pragma unroll
        for (int t = 0; t < 8; ++t) {
            #pragma unroll
            for (int s = 0; s < 4; ++s) {
                short8 bf = *(const short8*)(Bs + (t * 16 + m16) * AS_STRIDE + s * 32 + quad * 8);
                acc[t] = __builtin_amdgcn_mfma_f32_16x16x32_bf16(af[s], bf, acc[t], 0, 0, 0);
            }
        }

        // logit tile: C_L[row][n] with n<4 = a_src heads, 4..7 = a_dst heads
        f32x4 accL = (f32x4){0.f, 0.f, 0.f, 0.f};
        #pragma unroll
        for (int s = 0; s < 4; ++s) {
            uint4 bw = battf[s * 64 + lane];
            accL = __builtin_amdgcn_mfma_f32_16x16x32_bf16(af[s], *(short8*)&bw, accL, 0, 0, 0);
        }
        __syncthreads();   // done reading As/Bs; safe to alias with Cs

        // C layout: col = lane&15 (within tile), row = quad*4 + reg
        #pragma unroll
        for (int t = 0; t < 8; ++t)
            #pragma unroll
            for (int r = 0; r < 4; ++r)
                Cs[(w * 16 + quad * 4 + r) * CS_STRIDE + t * 16 + m16] = acc[t][r];
        __syncthreads();

        // epilogue: bf16 store only (logits already in accL)
        const int cp = lane;
        #pragma unroll
        for (int r = 0; r < 16; ++r) {
            int row = w * 16 + r;
            int row_g = rbase + row;
            float2 cv = *(const float2*)(Cs + row * CS_STRIDE + 2 * cp);
            ushort2 hs;
            hs.x = f2bf(cv.x); hs.y = f2bf(cv.y);
            if (row_g < NNODES) ((ushort2*)(hb + (size_t)row_g * 128))[cp] = hs;
        }
        // logit stores: accL[r] is row quad*4+r, col m16
        #pragma unroll
        for (int r = 0; r < 4; ++r) {
            int row_g = rbase + w * 16 + quad * 4 + r;
            if (row_g < NNODES) {
                if (m16 < 4)      a_src[row_g * 4 + m16]       = accL[r];
                else if (m16 < 8) a_dst[row_g * 4 + (m16 - 4)] = accL[r];
            }
        }
    }
}

// K3: gather per dst node. Lane = g*16+q (g = edge group, q = 16B chunk).
// Weight computed in-kernel: w = exp(leaky(a_src[sj][h] + a_dst[n][h])).
// Denominator summed in-register, folded into the shfl_xor(16/32) reduce.
// Round 9: window widened 16 -> 32 edges (8 per lane-group instead of 4) to
// DOUBLE the in-flight hb-row loads per lane (4 -> 8 x 16B). gather is
// latency-bound (35% HBM, 41% VALU in r0-r3) on random L2-miss reads; deeper
// MLP is the remaining lever. VGPR ~24 -> ~75 (still >=6 waves/SIMD).
// Clamped tail duplicates hit L1 (just-fetched line) -> negligible.
__global__ __launch_bounds__(256) void gather_k(const int* __restrict__ off,
                                                const int* __restrict__ csr,
                                                const unsigned short* __restrict__ hb,
                                                const float* __restrict__ a_src,
                                                const float* __restrict__ a_dst,
                                                const float* __restrict__ bias,
                                                float* __restrict__ out) {
    const int wid = threadIdx.x >> 6, lane = threadIdx.x & 63;
    const int n = blockIdx.x * 4 + wid;
    if (n >= NNODES) return;
    const int g = lane >> 4;         // edge slot within 4-wide group
    const int q = lane & 15;         // 16B chunk of the 256B row
    const int head_c = q >> 2;       // head of the channels this lane accumulates

    const float adn = a_dst[n * 4 + head_c];
    const float wsc = __expf(leaky(a_src[n * 4 + head_c] + adn));

    float acc[8];
    #pragma unroll
    for (int k = 0; k < 8; ++k) acc[k] = 0.f;
    float den = 0.f;

    if (g == 0) {   // self-loop seeds group 0
        uint4 hv = ((const uint4*)(hb + (size_t)n * 128))[q];
        acc[0] = wsc * __uint_as_float(hv.x << 16);
        acc[1] = wsc * __uint_as_float(hv.x & 0xffff0000u);
        acc[2] = wsc * __uint_as_float(hv.y << 16);
        acc[3] = wsc * __uint_as_float(hv.y & 0xffff0000u);
        acc[4] = wsc * __uint_as_float(hv.z << 16);
        acc[5] = wsc * __uint_as_float(hv.z & 0xffff0000u);
        acc[6] = wsc * __uint_as_float(hv.w << 16);
        acc[7] = wsc * __uint_as_float(hv.w & 0xffff0000u);
    }

    const int beg = off[n], end = off[n + 1];
    for (int base = beg; base < end; base += 32) {
        const int m = end - base < 32 ? end - base : 32;
        int sj[8];
        float as8[8];
        uint4 hv8[8];
        // phase 1: all csr loads (clamped, unconditional)
        #pragma unroll
        for (int jj = 0; jj < 8; ++jj) {
            int e = base + jj * 4 + g;
            if (e > end - 1) e = end - 1;
            sj[jj] = csr[e];
        }
        // phase 2: all dependent loads (a_src ∥ hb rows), 16 in flight
        #pragma unroll
        for (int jj = 0; jj < 8; ++jj) as8[jj] = a_src[sj[jj] * 4 + head_c];
        #pragma unroll
        for (int jj = 0; jj < 8; ++jj)
            hv8[jj] = ((const uint4*)(hb + (size_t)sj[jj] * 128))[q];
        // phase 3: VALU
        #pragma unroll
        for (int jj = 0; jj < 8; ++jj) {
            const int j = jj * 4 + g;
            float w = __expf(leaky(as8[jj] + adn));
            w = (j < m) ? w : 0.f;
            den += w;
            acc[0] += w * __uint_as_float(hv8[jj].x << 16);
            acc[1] += w * __uint_as_float(hv8[jj].x & 0xffff0000u);
            acc[2] += w * __uint_as_float(hv8[jj].y << 16);
            acc[3] += w * __uint_as_float(hv8[jj].y & 0xffff0000u);
            acc[4] += w * __uint_as_float(hv8[jj].z << 16);
            acc[5] += w * __uint_as_float(hv8[jj].z & 0xffff0000u);
            acc[6] += w * __uint_as_float(hv8[jj].w << 16);
            acc[7] += w * __uint_as_float(hv8[jj].w & 0xffff0000u);
        }
    }
    // reduce over the 4 edge-groups g (lane bits 4..5) at fixed q
    #pragma unroll
    for (int k = 0; k < 8; ++k) {
        acc[k] += __shfl_xor(acc[k], 16);
        acc[k] += __shfl_xor(acc[k], 32);
    }
    den += __shfl_xor(den, 16);
    den += __shfl_xor(den, 32);
    if (g == 0) {
        const float inv = __frcp_rn(den + wsc);
        float4 b0 = ((const float4*)bias)[2 * q];
        float4 b1 = ((const float4*)bias)[2 * q + 1];
        float4* orow = (float4*)(out + (size_t)n * 128);
        orow[2 * q]     = make_float4(acc[0] * inv + b0.x, acc[1] * inv + b0.y,
                                      acc[2] * inv + b0.z, acc[3] * inv + b0.w);
        orow[2 * q + 1] = make_float4(acc[4] * inv + b1.x, acc[5] * inv + b1.y,
                                      acc[6] * inv + b1.z, acc[7] * inv + b1.w);
    }
}

extern "C" void kernel_launch(void* const* d_in, const int* in_sizes, int n_in,
                              void* d_out, int out_size, void* d_ws, size_t ws_size,
                              hipStream_t stream) {
    const float* x     = (const float*)d_in[0];
    const int*   ei    = (const int*)d_in[1];   // int64 ref -> delivered int32
    const float* W     = (const float*)d_in[2];
    const float* att_s = (const float*)d_in[3];
    const float* att_d = (const float*)d_in[4];
    const float* bias  = (const float*)d_in[5];
    float*       out   = (float*)d_out;
    char*        ws    = (char*)d_ws;

    // ws layout (bytes):
    // hb (bf16) 12.8MB | a_src 0.8MB | a_dst 0.8MB | off 50177*4 | csr 3.2MB |
    // bktdata 4.01MB | bcnt 784B | wt 32KB | battf 4KB
    unsigned short* hb = (unsigned short*)(ws);
    float* a_src  = (float*)(ws + 12800000);
    float* a_dst  = (float*)(ws + 13600000);
    int*   off    = (int*)  (ws + 14400000);
    int*   csr    = (int*)  (ws + 14600768);
    unsigned int* bktdata = (unsigned int*)(ws + 17800768);
    int*   bcnt   = (int*)  (ws + 21814848);
    unsigned short* wt = (unsigned short*)(ws + 21815632);
    uint4* battf  = (uint4*)(ws + 21848400);

    hipMemsetAsync(bcnt, 0, NBKT * sizeof(int), stream);
    prep_k  <<<NBKT + 17, 256, 0, stream>>>(W, att_s, att_d, wt, battf,
                                            ei, bcnt, bktdata);
    main_k  <<<NBKT + GEMM_BLOCKS, 256, 0, stream>>>(x, wt, battf, hb,
                                                     a_src, a_dst, bcnt, bktdata,
                                                     off, csr);
    gather_k<<<12500, 256, 0, stream>>>(off, csr, hb, a_src, a_dst, bias, out);
}

// Round 10
// 150.660 us; speedup vs baseline: 1.0066x; 1.0066x over previous
//
#include <hip/hip_runtime.h>
#include <cstdint>

#define NNODES 50000
#define NEDGES 800000
#define NEG 0.2f
#define NBKT 196        // buckets of 256 nodes: 196*256 = 50176 >= 50000
#define BCAP 5120       // per-bucket capacity (mean 4096, sd 64 -> 16 sigma headroom)
#define GEMM_BLOCKS 391 // ceil(50000/128); 128 rows per block, B staged once

typedef __attribute__((ext_vector_type(8))) short short8;   // 8 bf16 (4 VGPRs)
typedef __attribute__((ext_vector_type(4))) float f32x4;

#define AS_STRIDE 136   // ushorts; 272B rows -> 16B aligned

__device__ __forceinline__ float leaky(float v) { return v > 0.f ? v : NEG * v; }

__device__ __forceinline__ unsigned short f2bf(float f) {   // round-to-nearest-even
    unsigned int u = __float_as_uint(f);
    u += 0x7fff + ((u >> 16) & 1);
    return (unsigned short)(u >> 16);
}

// block exclusive scan (shfl within wave + LDS across NW waves)
template <int NW>
__device__ __forceinline__ int block_excl_scan(int v, int t) {
    __shared__ int wsum[NW];
    const int lane = t & 63, wv = t >> 6;
    int x = v;
    #pragma unroll
    for (int m = 1; m < 64; m <<= 1) {
        int u = __shfl_up(x, m);
        if (lane >= m) x += u;
    }
    if (lane == 63) wsum[wv] = x;
    __syncthreads();
    if (t == 0) {
        int run = 0;
        #pragma unroll
        for (int i = 0; i < NW; ++i) { int tmp = wsum[i]; wsum[i] = run; run += tmp; }
    }
    __syncthreads();
    return x - v + wsum[wv];
}

// K1 prep: blocks [0,196) = edge binning by dst>>8 (the long pole, launched
// first); blocks [196,212) = W (fp32) -> Wt (bf16, n-major); block 212 =
// battf logit-fragment table. bin and wt have independent inputs ->
// co-scheduled instead of serialized.
__global__ __launch_bounds__(256) void prep_k(const float* __restrict__ W,
                                              const float* __restrict__ att_src,
                                              const float* __restrict__ att_dst,
                                              unsigned short* __restrict__ wt,
                                              uint4* __restrict__ battf,
                                              const int* __restrict__ ei,
                                              int* __restrict__ bcnt,
                                              unsigned int* __restrict__ bktdata) {
    __shared__ __align__(16) char smem[19712];
    const int t = threadIdx.x;

    if (blockIdx.x < NBKT) {
        // ---------------- BIN part ----------------
        int* lhist = (int*)smem;                    // [NBKT]
        int* lofs  = lhist + NBKT;
        int* lcur  = lofs + NBKT;
        int* gbase = lcur + NBKT;
        unsigned int* staged = (unsigned int*)(gbase + NBKT);  // [4096]
        const int b = blockIdx.x;
        for (int i = t; i < NBKT; i += 256) lhist[i] = 0;
        __syncthreads();
        unsigned int pk[16];
        int bk[16];
        const int e0 = b * 4096;
        #pragma unroll
        for (int i = 0; i < 16; ++i) {
            int e = e0 + i * 256 + t;
            if (e < NEDGES) {
                int s = ei[e], d = ei[NEDGES + e];
                bk[i] = d >> 8;
                pk[i] = ((unsigned)bk[i] << 24) | ((unsigned)(d & 255) << 16) | (unsigned)s;
                atomicAdd(&lhist[bk[i]], 1);
            } else bk[i] = -1;
        }
        __syncthreads();
        int v = (t < NBKT) ? lhist[t] : 0;
        int excl = block_excl_scan<4>(v, t);
        if (t < NBKT) { lofs[t] = excl; lcur[t] = excl; }
        __syncthreads();
        if (t < NBKT) gbase[t] = (v > 0) ? atomicAdd(&bcnt[t], v) : 0;
        #pragma unroll
        for (int i = 0; i < 16; ++i) {
            if (bk[i] >= 0) {
                int pos = atomicAdd(&lcur[bk[i]], 1);
                staged[pos] = pk[i];
            }
        }
        __syncthreads();
        const int total = lofs[NBKT - 1] + lhist[NBKT - 1];
        for (int i = t; i < total; i += 256) {
            unsigned int ent = staged[i];
            int bb = ent >> 24;
            int pos = gbase[bb] + (i - lofs[bb]);
            bktdata[(size_t)bb * BCAP + pos] = ent & 0x00FFFFFFu;
        }
    } else if (blockIdx.x < NBKT + 16) {
        // ---------------- Wt conversion ----------------
        int i = (blockIdx.x - NBKT) * 256 + t;   // [0, 4096)
        int k = i >> 5, n4 = (i & 31) * 4;
        float4 wv = ((const float4*)W)[i];
        wt[(n4 + 0) * 128 + k] = f2bf(wv.x);
        wt[(n4 + 1) * 128 + k] = f2bf(wv.y);
        wt[(n4 + 2) * 128 + k] = f2bf(wv.z);
        wt[(n4 + 3) * 128 + k] = f2bf(wv.w);
    } else {
        // ---------------- battf table ----------------
        float* wsd = (float*)smem;   // [2][128][4]
        const int k = t & 127, which = t >> 7;
        const float* av = which ? att_dst : att_src;
        #pragma unroll
        for (int h = 0; h < 4; ++h) {
            float s = 0.f;
            #pragma unroll
            for (int c4 = 0; c4 < 8; ++c4) {
                float4 wv = ((const float4*)(W + k * 128 + h * 32))[c4];
                float4 a  = ((const float4*)(av + h * 32))[c4];
                s += wv.x * a.x + wv.y * a.y + wv.z * a.z + wv.w * a.w;
            }
            wsd[(which * 128 + k) * 4 + h] = s;
        }
        __syncthreads();
        // battf[s*64+lane] = 8 bf16 of B_att[n=m16][k=s*32+quad*8+j]
        const int s = t >> 6, lane = t & 63;
        const int quad = lane >> 4, m16 = lane & 15;
        unsigned short fr[8];
        #pragma unroll
        for (int j = 0; j < 8; ++j) {
            int kk = s * 32 + quad * 8 + j;
            float v = 0.f;
            if (m16 < 4)      v = wsd[(0 * 128 + kk) * 4 + m16];
            else if (m16 < 8) v = wsd[(1 * 128 + kk) * 4 + (m16 - 4)];
            fr[j] = f2bf(v);
        }
        battf[s * 64 + lane] = make_uint4(
            ((unsigned)fr[1] << 16) | fr[0], ((unsigned)fr[3] << 16) | fr[2],
            ((unsigned)fr[5] << 16) | fr[4], ((unsigned)fr[7] << 16) | fr[6]);
    }
}

// K2 main: blocks [0,196) = per-bucket counting sort (overlaps the GEMM
// bulk); blocks [196,587) = bf16-MFMA gemm, 128 rows/block as TWO 64-row
// tiles REUSING the staged B (halves Wt staging + block-count overhead).
// Epilogue stores bf16 DIRECTLY from the accumulator (per (t,r) a wave
// writes 4x32B segments; L2 write-combines) — the old Cs LDS round-trip
// (32 writes + 32 reads/thread + extra barrier) is deleted, which is also
// what frees the LDS to keep Bs alive across both tiles.
__global__ __launch_bounds__(256) void main_k(const float* __restrict__ x,
                                              const unsigned short* __restrict__ wt,
                                              const uint4* __restrict__ battf,
                                              unsigned short* __restrict__ hb,
                                              float* __restrict__ a_src,
                                              float* __restrict__ a_dst,
                                              const int* __restrict__ bcnt,
                                              const unsigned int* __restrict__ bktdata,
                                              int* __restrict__ off,
                                              int* __restrict__ csr) {
    __shared__ __align__(16) char smem[52224];
    const int tid = threadIdx.x;

    if (blockIdx.x < NBKT) {
        // ---------------- SORT part ----------------
        unsigned int* staged = (unsigned int*)smem;        // [BCAP] 20480B
        int* lcnt = (int*)(smem + 20480);                  // [256]
        int* lcur = (int*)(smem + 21504);                  // [256]
        __shared__ int sbase, scnt;
        const int b = blockIdx.x, t = tid;
        int bv = (t < NBKT) ? bcnt[t] : 0;
        int bexcl = block_excl_scan<4>(bv, t);
        if (t == b) { sbase = bexcl; scnt = bv; }
        lcnt[t] = 0;
        __syncthreads();
        const int cnt = scnt, base = sbase;
        for (int i = t; i < cnt; i += 256) staged[i] = bktdata[(size_t)b * BCAP + i];
        __syncthreads();
        for (int i = t; i < cnt; i += 256) atomicAdd(&lcnt[(staged[i] >> 16) & 0xFF], 1);
        __syncthreads();
        int v = lcnt[t];
        int excl = block_excl_scan<4>(v, t);
        lcur[t] = excl;
        const int node = b * 256 + t;
        if (node <= NNODES) off[node] = base + excl;
        __syncthreads();
        for (int i = t; i < cnt; i += 256) {
            unsigned int ent = staged[i];
            int pos = atomicAdd(&lcur[(ent >> 16) & 0xFF], 1);
            csr[base + pos] = (int)(ent & 0xFFFFu);
        }
    } else {
        // ---------------- GEMM part ----------------
        unsigned short* As = (unsigned short*)smem;            // [64][AS_STRIDE] bf16
        unsigned short* Bs = (unsigned short*)(smem + 17408);  // WT [128][AS_STRIDE] bf16
        const int bb = blockIdx.x - NBKT;      // [0, 391)

        // stage B ONCE: Wt (bf16, n-major) -> LDS, 16B chunks, coalesced
        #pragma unroll
        for (int i = 0; i < 8; ++i) {
            int c = tid + i * 256;           // 16B chunk id, [0, 2048)
            int n = c >> 4, k8 = (c & 15) * 8;
            uint4 wv = ((const uint4*)wt)[c];
            *(uint4*)(Bs + n * AS_STRIDE + k8) = wv;
        }

        const int lane = tid & 63, w = tid >> 6;
        const int quad = lane >> 4, m16 = lane & 15;

        #pragma unroll
        for (int u = 0; u < 2; ++u) {
            const int rbase = bb * 128 + u * 64;

            // stage A: x rows fp32 -> bf16 LDS
            #pragma unroll
            for (int i = 0; i < 8; ++i) {
                int f = tid + i * 256;           // float4 index; 32 per row
                int r = f >> 5, c4 = (f & 31) * 4;
                float4 xv = make_float4(0.f, 0.f, 0.f, 0.f);
                if (rbase + r < NNODES) xv = ((const float4*)x)[(size_t)(rbase + r) * 32 + (f & 31)];
                unsigned int p0 = ((unsigned int)f2bf(xv.y) << 16) | f2bf(xv.x);
                unsigned int p1 = ((unsigned int)f2bf(xv.w) << 16) | f2bf(xv.z);
                *(uint2*)(As + r * AS_STRIDE + c4) = make_uint2(p0, p1);
            }
            __syncthreads();   // A (and, for u=0, B) staged

            short8 af[4];
            #pragma unroll
            for (int s = 0; s < 4; ++s)
                af[s] = *(const short8*)(As + (w * 16 + m16) * AS_STRIDE + s * 32 + quad * 8);

            f32x4 acc[8];
            #pragma unroll
            for (int t = 0; t < 8; ++t) acc[t] = (f32x4){0.f, 0.f, 0.f, 0.f};

            #pragma unroll
            for (int t = 0; t < 8; ++t) {
                #pragma unroll
                for (int s = 0; s < 4; ++s) {
                    short8 bf = *(const short8*)(Bs + (t * 16 + m16) * AS_STRIDE + s * 32 + quad * 8);
                    acc[t] = __builtin_amdgcn_mfma_f32_16x16x32_bf16(af[s], bf, acc[t], 0, 0, 0);
                }
            }

            // logit tile: C_L[row][n], n<4 = a_src heads, 4..7 = a_dst heads
            f32x4 accL = (f32x4){0.f, 0.f, 0.f, 0.f};
            #pragma unroll
            for (int s = 0; s < 4; ++s) {
                uint4 bw = battf[s * 64 + lane];
                accL = __builtin_amdgcn_mfma_f32_16x16x32_bf16(af[s], *(short8*)&bw, accL, 0, 0, 0);
            }

            // direct epilogue: C frag (row=quad*4+r, col=t*16+m16) -> hb
            #pragma unroll
            for (int t = 0; t < 8; ++t)
                #pragma unroll
                for (int r = 0; r < 4; ++r) {
                    int row_g = rbase + w * 16 + quad * 4 + r;
                    if (row_g < NNODES)
                        hb[(size_t)row_g * 128 + t * 16 + m16] = f2bf(acc[t][r]);
                }
            // logit stores: accL[r] is row quad*4+r, col m16
            #pragma unroll
            for (int r = 0; r < 4; ++r) {
                int row_g = rbase + w * 16 + quad * 4 + r;
                if (row_g < NNODES) {
                    if (m16 < 4)      a_src[row_g * 4 + m16]       = accL[r];
                    else if (m16 < 8) a_dst[row_g * 4 + (m16 - 4)] = accL[r];
                }
            }
            __syncthreads();   // all waves done with As before restaging
        }
    }
}

// K3: gather per dst node (r8-verified version; r9's 32-edge window REVERTED
// — it doubled VALU work via clamped-duplicate slots, VALUBusy 41->65%, no
// duration change: gather is pinned ~44us by the structural 8-XCD x 12.8MB
// hb L2-refetch, FETCH_SIZE ~96MB). Lane = g*16+q. Weight computed
// in-kernel; denominator in-register via the shfl_xor(16/32) reduce; loads
// index-clamped and unconditional.
__global__ __launch_bounds__(256) void gather_k(const int* __restrict__ off,
                                                const int* __restrict__ csr,
                                                const unsigned short* __restrict__ hb,
                                                const float* __restrict__ a_src,
                                                const float* __restrict__ a_dst,
                                                const float* __restrict__ bias,
                                                float* __restrict__ out) {
    const int wid = threadIdx.x >> 6, lane = threadIdx.x & 63;
    const int n = blockIdx.x * 4 + wid;
    if (n >= NNODES) return;
    const int g = lane >> 4;         // edge slot within 4-wide group
    const int q = lane & 15;         // 16B chunk of the 256B row
    const int head_c = q >> 2;       // head of the channels this lane accumulates

    const float adn = a_dst[n * 4 + head_c];
    const float wsc = __expf(leaky(a_src[n * 4 + head_c] + adn));

    float acc[8];
    #pragma unroll
    for (int k = 0; k < 8; ++k) acc[k] = 0.f;
    float den = 0.f;

    if (g == 0) {   // self-loop seeds group 0
        uint4 hv = ((const uint4*)(hb + (size_t)n * 128))[q];
        acc[0] = wsc * __uint_as_float(hv.x << 16);
        acc[1] = wsc * __uint_as_float(hv.x & 0xffff0000u);
        acc[2] = wsc * __uint_as_float(hv.y << 16);
        acc[3] = wsc * __uint_as_float(hv.y & 0xffff0000u);
        acc[4] = wsc * __uint_as_float(hv.z << 16);
        acc[5] = wsc * __uint_as_float(hv.z & 0xffff0000u);
        acc[6] = wsc * __uint_as_float(hv.w << 16);
        acc[7] = wsc * __uint_as_float(hv.w & 0xffff0000u);
    }

    const int beg = off[n], end = off[n + 1];
    for (int base = beg; base < end; base += 16) {
        const int m = end - base < 16 ? end - base : 16;
        int sj[4];
        float as4[4];
        uint4 hv4[4];
        // phase 1: all csr loads (clamped, unconditional)
        #pragma unroll
        for (int jj = 0; jj < 4; ++jj) {
            int e = base + jj * 4 + g;
            if (e > end - 1) e = end - 1;
            sj[jj] = csr[e];
        }
        // phase 2: all dependent loads (a_src ∥ hb rows), 8 in flight
        #pragma unroll
        for (int jj = 0; jj < 4; ++jj) as4[jj] = a_src[sj[jj] * 4 + head_c];
        #pragma unroll
        for (int jj = 0; jj < 4; ++jj)
            hv4[jj] = ((const uint4*)(hb + (size_t)sj[jj] * 128))[q];
        // phase 3: VALU
        #pragma unroll
        for (int jj = 0; jj < 4; ++jj) {
            const int j = jj * 4 + g;
            float w = __expf(leaky(as4[jj] + adn));
            w = (j < m) ? w : 0.f;
            den += w;
            acc[0] += w * __uint_as_float(hv4[jj].x << 16);
            acc[1] += w * __uint_as_float(hv4[jj].x & 0xffff0000u);
            acc[2] += w * __uint_as_float(hv4[jj].y << 16);
            acc[3] += w * __uint_as_float(hv4[jj].y & 0xffff0000u);
            acc[4] += w * __uint_as_float(hv4[jj].z << 16);
            acc[5] += w * __uint_as_float(hv4[jj].z & 0xffff0000u);
            acc[6] += w * __uint_as_float(hv4[jj].w << 16);
            acc[7] += w * __uint_as_float(hv4[jj].w & 0xffff0000u);
        }
    }
    // reduce over the 4 edge-groups g (lane bits 4..5) at fixed q
    #pragma unroll
    for (int k = 0; k < 8; ++k) {
        acc[k] += __shfl_xor(acc[k], 16);
        acc[k] += __shfl_xor(acc[k], 32);
    }
    den += __shfl_xor(den, 16);
    den += __shfl_xor(den, 32);
    if (g == 0) {
        const float inv = __frcp_rn(den + wsc);
        float4 b0 = ((const float4*)bias)[2 * q];
        float4 b1 = ((const float4*)bias)[2 * q + 1];
        float4* orow = (float4*)(out + (size_t)n * 128);
        orow[2 * q]     = make_float4(acc[0] * inv + b0.x, acc[1] * inv + b0.y,
                                      acc[2] * inv + b0.z, acc[3] * inv + b0.w);
        orow[2 * q + 1] = make_float4(acc[4] * inv + b1.x, acc[5] * inv + b1.y,
                                      acc[6] * inv + b1.z, acc[7] * inv + b1.w);
    }
}

extern "C" void kernel_launch(void* const* d_in, const int* in_sizes, int n_in,
                              void* d_out, int out_size, void* d_ws, size_t ws_size,
                              hipStream_t stream) {
    const float* x     = (const float*)d_in[0];
    const int*   ei    = (const int*)d_in[1];   // int64 ref -> delivered int32
    const float* W     = (const float*)d_in[2];
    const float* att_s = (const float*)d_in[3];
    const float* att_d = (const float*)d_in[4];
    const float* bias  = (const float*)d_in[5];
    float*       out   = (float*)d_out;
    char*        ws    = (char*)d_ws;

    // ws layout (bytes):
    // hb (bf16) 12.8MB | a_src 0.8MB | a_dst 0.8MB | off 50177*4 | csr 3.2MB |
    // bktdata 4.01MB | bcnt 784B | wt 32KB | battf 4KB
    unsigned short* hb = (unsigned short*)(ws);
    float* a_src  = (float*)(ws + 12800000);
    float* a_dst  = (float*)(ws + 13600000);
    int*   off    = (int*)  (ws + 14400000);
    int*   csr    = (int*)  (ws + 14600768);
    unsigned int* bktdata = (unsigned int*)(ws + 17800768);
    int*   bcnt   = (int*)  (ws + 21814848);
    unsigned short* wt = (unsigned short*)(ws + 21815632);
    uint4* battf  = (uint4*)(ws + 21848400);

    hipMemsetAsync(bcnt, 0, NBKT * sizeof(int), stream);
    prep_k  <<<NBKT + 17, 256, 0, stream>>>(W, att_s, att_d, wt, battf,
                                            ei, bcnt, bktdata);
    main_k  <<<NBKT + GEMM_BLOCKS, 256, 0, stream>>>(x, wt, battf, hb,
                                                     a_src, a_dst, bcnt, bktdata,
                                                     off, csr);
    gather_k<<<12500, 256, 0, stream>>>(off, csr, hb, a_src, a_dst, bias, out);
}

// Round 11
// 143.575 us; speedup vs baseline: 1.0563x; 1.0493x over previous
//
#include <hip/hip_runtime.h>
#include <cstdint>

#define NNODES 50000
#define NEDGES 800000
#define NEDGES4 200000  // NEDGES/4: int4 loads never straddle the boundary
#define NEG 0.2f
#define NBKT 196        // buckets of 256 nodes: 196*256 = 50176 >= 50000
#define BCAP 5120       // per-bucket capacity (mean 4096, sd 64 -> 16 sigma headroom)
#define GEMM_BLOCKS 782 // ceil(50000/64)

typedef __attribute__((ext_vector_type(8))) short short8;   // 8 bf16 (4 VGPRs)
typedef __attribute__((ext_vector_type(4))) float f32x4;

#define AS_STRIDE 136   // ushorts; 272B rows -> 16B aligned
#define CS_STRIDE 132   // floats; breaks 128-mod-32 bank aliasing

__device__ __forceinline__ float leaky(float v) { return v > 0.f ? v : NEG * v; }

__device__ __forceinline__ unsigned short f2bf(float f) {   // round-to-nearest-even
    unsigned int u = __float_as_uint(f);
    u += 0x7fff + ((u >> 16) & 1);
    return (unsigned short)(u >> 16);
}

// block exclusive scan (shfl within wave + LDS across NW waves)
template <int NW>
__device__ __forceinline__ int block_excl_scan(int v, int t) {
    __shared__ int wsum[NW];
    const int lane = t & 63, wv = t >> 6;
    int x = v;
    #pragma unroll
    for (int m = 1; m < 64; m <<= 1) {
        int u = __shfl_up(x, m);
        if (lane >= m) x += u;
    }
    if (lane == 63) wsum[wv] = x;
    __syncthreads();
    if (t == 0) {
        int run = 0;
        #pragma unroll
        for (int i = 0; i < NW; ++i) { int tmp = wsum[i]; wsum[i] = run; run += tmp; }
    }
    __syncthreads();
    return x - v + wsum[wv];
}

// K1 prep: blocks [0,196) = edge binning by dst>>8 (int4-vectorized ei loads:
// 32 scalar 4B loads/thread -> 8 x 16B, same coalescing); blocks [196,212) =
// W -> Wt (bf16, n-major); block 212 = battf logit-fragment table.
__global__ __launch_bounds__(256) void prep_k(const float* __restrict__ W,
                                              const float* __restrict__ att_src,
                                              const float* __restrict__ att_dst,
                                              unsigned short* __restrict__ wt,
                                              uint4* __restrict__ battf,
                                              const int* __restrict__ ei,
                                              int* __restrict__ bcnt,
                                              unsigned int* __restrict__ bktdata) {
    __shared__ __align__(16) char smem[19712];
    const int t = threadIdx.x;

    if (blockIdx.x < NBKT) {
        // ---------------- BIN part ----------------
        int* lhist = (int*)smem;                    // [NBKT]
        int* lofs  = lhist + NBKT;
        int* lcur  = lofs + NBKT;
        int* gbase = lcur + NBKT;
        unsigned int* staged = (unsigned int*)(gbase + NBKT);  // [4096]
        const int b = blockIdx.x;
        for (int i = t; i < NBKT; i += 256) lhist[i] = 0;
        __syncthreads();
        unsigned int pk[16];
        int bk[16];
        #pragma unroll
        for (int i = 0; i < 4; ++i) {
            int e4 = b * 1024 + i * 256 + t;      // int4 index into src/dst
            if (e4 < NEDGES4) {
                int4 sv = ((const int4*)ei)[e4];
                int4 dv = ((const int4*)ei)[NEDGES4 + e4];
                int ss[4] = {sv.x, sv.y, sv.z, sv.w};
                int dd[4] = {dv.x, dv.y, dv.z, dv.w};
                #pragma unroll
                for (int c = 0; c < 4; ++c) {
                    int bkt = dd[c] >> 8;
                    bk[i * 4 + c] = bkt;
                    pk[i * 4 + c] = ((unsigned)bkt << 24) |
                                    ((unsigned)(dd[c] & 255) << 16) | (unsigned)ss[c];
                    atomicAdd(&lhist[bkt], 1);
                }
            } else {
                #pragma unroll
                for (int c = 0; c < 4; ++c) bk[i * 4 + c] = -1;
            }
        }
        __syncthreads();
        int v = (t < NBKT) ? lhist[t] : 0;
        int excl = block_excl_scan<4>(v, t);
        if (t < NBKT) { lofs[t] = excl; lcur[t] = excl; }
        __syncthreads();
        if (t < NBKT) gbase[t] = (v > 0) ? atomicAdd(&bcnt[t], v) : 0;
        #pragma unroll
        for (int i = 0; i < 16; ++i) {
            if (bk[i] >= 0) {
                int pos = atomicAdd(&lcur[bk[i]], 1);
                staged[pos] = pk[i];
            }
        }
        __syncthreads();
        const int total = lofs[NBKT - 1] + lhist[NBKT - 1];
        for (int i = t; i < total; i += 256) {
            unsigned int ent = staged[i];
            int bb = ent >> 24;
            int pos = gbase[bb] + (i - lofs[bb]);
            bktdata[(size_t)bb * BCAP + pos] = ent & 0x00FFFFFFu;
        }
    } else if (blockIdx.x < NBKT + 16) {
        // ---------------- Wt conversion ----------------
        int i = (blockIdx.x - NBKT) * 256 + t;   // [0, 4096)
        int k = i >> 5, n4 = (i & 31) * 4;
        float4 wv = ((const float4*)W)[i];
        wt[(n4 + 0) * 128 + k] = f2bf(wv.x);
        wt[(n4 + 1) * 128 + k] = f2bf(wv.y);
        wt[(n4 + 2) * 128 + k] = f2bf(wv.z);
        wt[(n4 + 3) * 128 + k] = f2bf(wv.w);
    } else {
        // ---------------- battf table ----------------
        float* wsd = (float*)smem;   // [2][128][4]
        const int k = t & 127, which = t >> 7;
        const float* av = which ? att_dst : att_src;
        #pragma unroll
        for (int h = 0; h < 4; ++h) {
            float s = 0.f;
            #pragma unroll
            for (int c4 = 0; c4 < 8; ++c4) {
                float4 wv = ((const float4*)(W + k * 128 + h * 32))[c4];
                float4 a  = ((const float4*)(av + h * 32))[c4];
                s += wv.x * a.x + wv.y * a.y + wv.z * a.z + wv.w * a.w;
            }
            wsd[(which * 128 + k) * 4 + h] = s;
        }
        __syncthreads();
        // battf[s*64+lane] = 8 bf16 of B_att[n=m16][k=s*32+quad*8+j]
        const int s = t >> 6, lane = t & 63;
        const int quad = lane >> 4, m16 = lane & 15;
        unsigned short fr[8];
        #pragma unroll
        for (int j = 0; j < 8; ++j) {
            int kk = s * 32 + quad * 8 + j;
            float v = 0.f;
            if (m16 < 4)      v = wsd[(0 * 128 + kk) * 4 + m16];
            else if (m16 < 8) v = wsd[(1 * 128 + kk) * 4 + (m16 - 4)];
            fr[j] = f2bf(v);
        }
        battf[s * 64 + lane] = make_uint4(
            ((unsigned)fr[1] << 16) | fr[0], ((unsigned)fr[3] << 16) | fr[2],
            ((unsigned)fr[5] << 16) | fr[4], ((unsigned)fr[7] << 16) | fr[6]);
    }
}

// K2 main: blocks [0,196) = per-bucket counting sort (uint4-staged; overlaps
// the GEMM bulk); blocks [196,978) = bf16-MFMA gemm — r8-verified form: 64
// rows/block, B staged per block, C coalesced via the Cs LDS round-trip.
// (r10's direct-store + 128-row variant REGRESSED ~6us: 2B scalar stores x32
// per thread lose more than the LDS round-trip costs, and 391 blocks cut the
// TLP co-hiding the sort blocks.)
__global__ __launch_bounds__(256) void main_k(const float* __restrict__ x,
                                              const unsigned short* __restrict__ wt,
                                              const uint4* __restrict__ battf,
                                              unsigned short* __restrict__ hb,
                                              float* __restrict__ a_src,
                                              float* __restrict__ a_dst,
                                              const int* __restrict__ bcnt,
                                              const unsigned int* __restrict__ bktdata,
                                              int* __restrict__ off,
                                              int* __restrict__ csr) {
    __shared__ __align__(16) char smem[52224];
    const int tid = threadIdx.x;

    if (blockIdx.x < NBKT) {
        // ---------------- SORT part ----------------
        unsigned int* staged = (unsigned int*)smem;        // [BCAP] 20480B
        int* lcnt = (int*)(smem + 20480);                  // [256]
        int* lcur = (int*)(smem + 21504);                  // [256]
        __shared__ int sbase, scnt;
        const int b = blockIdx.x, t = tid;
        int bv = (t < NBKT) ? bcnt[t] : 0;
        int bexcl = block_excl_scan<4>(bv, t);
        if (t == b) { sbase = bexcl; scnt = bv; }
        lcnt[t] = 0;
        __syncthreads();
        const int cnt = scnt, base = sbase;
        // uint4 staging (BCAP%4==0; tail reads stay inside the bucket slot;
        // staged words beyond cnt are never read)
        const int cnt4 = (cnt + 3) >> 2;
        for (int i = t; i < cnt4; i += 256)
            ((uint4*)staged)[i] = ((const uint4*)(bktdata + (size_t)b * BCAP))[i];
        __syncthreads();
        for (int i = t; i < cnt; i += 256) atomicAdd(&lcnt[(staged[i] >> 16) & 0xFF], 1);
        __syncthreads();
        int v = lcnt[t];
        int excl = block_excl_scan<4>(v, t);
        lcur[t] = excl;
        const int node = b * 256 + t;
        if (node <= NNODES) off[node] = base + excl;
        __syncthreads();
        for (int i = t; i < cnt; i += 256) {
            unsigned int ent = staged[i];
            int pos = atomicAdd(&lcur[(ent >> 16) & 0xFF], 1);
            csr[base + pos] = (int)(ent & 0xFFFFu);
        }
    } else {
        // ---------------- GEMM part ----------------
        unsigned short* As = (unsigned short*)smem;            // [64][AS_STRIDE] bf16
        unsigned short* Bs = (unsigned short*)(smem + 17408);  // WT [128][AS_STRIDE] bf16
        float*          Cs = (float*)smem;                     // [64][CS_STRIDE] fp32 (aliases)
        const int rbase = (blockIdx.x - NBKT) * 64;

        // stage A: x rows fp32 -> bf16 LDS
        #pragma unroll
        for (int i = 0; i < 8; ++i) {
            int f = tid + i * 256;           // float4 index; 32 per row
            int r = f >> 5, c4 = (f & 31) * 4;
            float4 xv = make_float4(0.f, 0.f, 0.f, 0.f);
            if (rbase + r < NNODES) xv = ((const float4*)x)[(size_t)(rbase + r) * 32 + (f & 31)];
            unsigned int p0 = ((unsigned int)f2bf(xv.y) << 16) | f2bf(xv.x);
            unsigned int p1 = ((unsigned int)f2bf(xv.w) << 16) | f2bf(xv.z);
            *(uint2*)(As + r * AS_STRIDE + c4) = make_uint2(p0, p1);
        }
        // stage B: Wt (bf16, n-major) -> LDS, 16B chunks, coalesced
        #pragma unroll
        for (int i = 0; i < 8; ++i) {
            int c = tid + i * 256;           // 16B chunk id, [0, 2048)
            int n = c >> 4, k8 = (c & 15) * 8;
            uint4 wv = ((const uint4*)wt)[c];
            *(uint4*)(Bs + n * AS_STRIDE + k8) = wv;
        }
        __syncthreads();

        const int lane = tid & 63, w = tid >> 6;
        const int quad = lane >> 4, m16 = lane & 15;

        short8 af[4];
        #pragma unroll
        for (int s = 0; s < 4; ++s)
            af[s] = *(const short8*)(As + (w * 16 + m16) * AS_STRIDE + s * 32 + quad * 8);

        f32x4 acc[8];
        #pragma unroll
        for (int t = 0; t < 8; ++t) acc[t] = (f32x4){0.f, 0.f, 0.f, 0.f};

        #pragma unroll
        for (int t = 0; t < 8; ++t) {
            #pragma unroll
            for (int s = 0; s < 4; ++s) {
                short8 bf = *(const short8*)(Bs + (t * 16 + m16) * AS_STRIDE + s * 32 + quad * 8);
                acc[t] = __builtin_amdgcn_mfma_f32_16x16x32_bf16(af[s], bf, acc[t], 0, 0, 0);
            }
        }

        // logit tile: C_L[row][n] with n<4 = a_src heads, 4..7 = a_dst heads
        f32x4 accL = (f32x4){0.f, 0.f, 0.f, 0.f};
        #pragma unroll
        for (int s = 0; s < 4; ++s) {
            uint4 bw = battf[s * 64 + lane];
            accL = __builtin_amdgcn_mfma_f32_16x16x32_bf16(af[s], *(short8*)&bw, accL, 0, 0, 0);
        }
        __syncthreads();   // done reading As/Bs; safe to alias with Cs

        // C layout: col = lane&15 (within tile), row = quad*4 + reg
        #pragma unroll
        for (int t = 0; t < 8; ++t)
            #pragma unroll
            for (int r = 0; r < 4; ++r)
                Cs[(w * 16 + quad * 4 + r) * CS_STRIDE + t * 16 + m16] = acc[t][r];
        __syncthreads();

        // epilogue: coalesced bf16 store (logits already in accL)
        const int cp = lane;
        #pragma unroll
        for (int r = 0; r < 16; ++r) {
            int row = w * 16 + r;
            int row_g = rbase + row;
            float2 cv = *(const float2*)(Cs + row * CS_STRIDE + 2 * cp);
            ushort2 hs;
            hs.x = f2bf(cv.x); hs.y = f2bf(cv.y);
            if (row_g < NNODES) ((ushort2*)(hb + (size_t)row_g * 128))[cp] = hs;
        }
        // logit stores: accL[r] is row quad*4+r, col m16
        #pragma unroll
        for (int r = 0; r < 4; ++r) {
            int row_g = rbase + w * 16 + quad * 4 + r;
            if (row_g < NNODES) {
                if (m16 < 4)      a_src[row_g * 4 + m16]       = accL[r];
                else if (m16 < 8) a_dst[row_g * 4 + (m16 - 4)] = accL[r];
            }
        }
    }
}

// K3: gather per dst node (r8-verified version). Lane = g*16+q. Weight
// computed in-kernel; denominator in-register via the shfl_xor(16/32)
// reduce; loads index-clamped and unconditional. Pinned ~44us by the
// structural 8-XCD x 12.8MB hb L2-refetch (FETCH ~96MB) — r9's deeper-MLP
// attempt confirmed latency is NOT per-wave-limited.
__global__ __launch_bounds__(256) void gather_k(const int* __restrict__ off,
                                                const int* __restrict__ csr,
                                                const unsigned short* __restrict__ hb,
                                                const float* __restrict__ a_src,
                                                const float* __restrict__ a_dst,
                                                const float* __restrict__ bias,
                                                float* __restrict__ out) {
    const int wid = threadIdx.x >> 6, lane = threadIdx.x & 63;
    const int n = blockIdx.x * 4 + wid;
    if (n >= NNODES) return;
    const int g = lane >> 4;         // edge slot within 4-wide group
    const int q = lane & 15;         // 16B chunk of the 256B row
    const int head_c = q >> 2;       // head of the channels this lane accumulates

    const float adn = a_dst[n * 4 + head_c];
    const float wsc = __expf(leaky(a_src[n * 4 + head_c] + adn));

    float acc[8];
    #pragma unroll
    for (int k = 0; k < 8; ++k) acc[k] = 0.f;
    float den = 0.f;

    if (g == 0) {   // self-loop seeds group 0
        uint4 hv = ((const uint4*)(hb + (size_t)n * 128))[q];
        acc[0] = wsc * __uint_as_float(hv.x << 16);
        acc[1] = wsc * __uint_as_float(hv.x & 0xffff0000u);
        acc[2] = wsc * __uint_as_float(hv.y << 16);
        acc[3] = wsc * __uint_as_float(hv.y & 0xffff0000u);
        acc[4] = wsc * __uint_as_float(hv.z << 16);
        acc[5] = wsc * __uint_as_float(hv.z & 0xffff0000u);
        acc[6] = wsc * __uint_as_float(hv.w << 16);
        acc[7] = wsc * __uint_as_float(hv.w & 0xffff0000u);
    }

    const int beg = off[n], end = off[n + 1];
    for (int base = beg; base < end; base += 16) {
        const int m = end - base < 16 ? end - base : 16;
        int sj[4];
        float as4[4];
        uint4 hv4[4];
        // phase 1: all csr loads (clamped, unconditional)
        #pragma unroll
        for (int jj = 0; jj < 4; ++jj) {
            int e = base + jj * 4 + g;
            if (e > end - 1) e = end - 1;
            sj[jj] = csr[e];
        }
        // phase 2: all dependent loads (a_src ∥ hb rows), 8 in flight
        #pragma unroll
        for (int jj = 0; jj < 4; ++jj) as4[jj] = a_src[sj[jj] * 4 + head_c];
        #pragma unroll
        for (int jj = 0; jj < 4; ++jj)
            hv4[jj] = ((const uint4*)(hb + (size_t)sj[jj] * 128))[q];
        // phase 3: VALU
        #pragma unroll
        for (int jj = 0; jj < 4; ++jj) {
            const int j = jj * 4 + g;
            float w = __expf(leaky(as4[jj] + adn));
            w = (j < m) ? w : 0.f;
            den += w;
            acc[0] += w * __uint_as_float(hv4[jj].x << 16);
            acc[1] += w * __uint_as_float(hv4[jj].x & 0xffff0000u);
            acc[2] += w * __uint_as_float(hv4[jj].y << 16);
            acc[3] += w * __uint_as_float(hv4[jj].y & 0xffff0000u);
            acc[4] += w * __uint_as_float(hv4[jj].z << 16);
            acc[5] += w * __uint_as_float(hv4[jj].z & 0xffff0000u);
            acc[6] += w * __uint_as_float(hv4[jj].w << 16);
            acc[7] += w * __uint_as_float(hv4[jj].w & 0xffff0000u);
        }
    }
    // reduce over the 4 edge-groups g (lane bits 4..5) at fixed q
    #pragma unroll
    for (int k = 0; k < 8; ++k) {
        acc[k] += __shfl_xor(acc[k], 16);
        acc[k] += __shfl_xor(acc[k], 32);
    }
    den += __shfl_xor(den, 16);
    den += __shfl_xor(den, 32);
    if (g == 0) {
        const float inv = __frcp_rn(den + wsc);
        float4 b0 = ((const float4*)bias)[2 * q];
        float4 b1 = ((const float4*)bias)[2 * q + 1];
        float4* orow = (float4*)(out + (size_t)n * 128);
        orow[2 * q]     = make_float4(acc[0] * inv + b0.x, acc[1] * inv + b0.y,
                                      acc[2] * inv + b0.z, acc[3] * inv + b0.w);
        orow[2 * q + 1] = make_float4(acc[4] * inv + b1.x, acc[5] * inv + b1.y,
                                      acc[6] * inv + b1.z, acc[7] * inv + b1.w);
    }
}

extern "C" void kernel_launch(void* const* d_in, const int* in_sizes, int n_in,
                              void* d_out, int out_size, void* d_ws, size_t ws_size,
                              hipStream_t stream) {
    const float* x     = (const float*)d_in[0];
    const int*   ei    = (const int*)d_in[1];   // int64 ref -> delivered int32
    const float* W     = (const float*)d_in[2];
    const float* att_s = (const float*)d_in[3];
    const float* att_d = (const float*)d_in[4];
    const float* bias  = (const float*)d_in[5];
    float*       out   = (float*)d_out;
    char*        ws    = (char*)d_ws;

    // ws layout (bytes):
    // hb (bf16) 12.8MB | a_src 0.8MB | a_dst 0.8MB | off 50177*4 | csr 3.2MB |
    // bktdata 4.01MB | bcnt 784B | wt 32KB | battf 4KB
    unsigned short* hb = (unsigned short*)(ws);
    float* a_src  = (float*)(ws + 12800000);
    float* a_dst  = (float*)(ws + 13600000);
    int*   off    = (int*)  (ws + 14400000);
    int*   csr    = (int*)  (ws + 14600768);
    unsigned int* bktdata = (unsigned int*)(ws + 17800768);
    int*   bcnt   = (int*)  (ws + 21814848);
    unsigned short* wt = (unsigned short*)(ws + 21815632);
    uint4* battf  = (uint4*)(ws + 21848400);

    hipMemsetAsync(bcnt, 0, NBKT * sizeof(int), stream);
    prep_k  <<<NBKT + 17, 256, 0, stream>>>(W, att_s, att_d, wt, battf,
                                            ei, bcnt, bktdata);
    main_k  <<<NBKT + GEMM_BLOCKS, 256, 0, stream>>>(x, wt, battf, hb,
                                                     a_src, a_dst, bcnt, bktdata,
                                                     off, csr);
    gather_k<<<12500, 256, 0, stream>>>(off, csr, hb, a_src, a_dst, bias, out);
}